// Round 2
// baseline (9032.021 us; speedup 1.0000x reference)
//
#include <hip/hip_runtime.h>
#include <hip/hip_bf16.h>

#define NN  100000
#define NE  1600000
#define NH4 400000      // N*H
#define NHC 12800000    // N*HC

// ---- GEMM: out[N,128] = A[N,128] @ W[128,128] (+ bias1 + bias2) ----
__global__ __launch_bounds__(256) void gemm128_k(const float* __restrict__ A,
                                                 const float* __restrict__ W,
                                                 float* __restrict__ out,
                                                 const float* __restrict__ bias1,
                                                 const float* __restrict__ bias2) {
  __shared__ float As[32 * 128];   // 16 KB
  __shared__ float Wsh[64 * 128];  // 32 KB
  const int tid = threadIdx.x;
  const int row0 = blockIdx.x * 32;
  {
    const float4* __restrict__ Ag = (const float4*)(A + row0 * 128);
    float4* Al = (float4*)As;
#pragma unroll
    for (int i = 0; i < 4; i++) Al[tid + 256 * i] = Ag[tid + 256 * i];
  }

  const int c = tid & 127, rh = tid >> 7;
  float acc[16];
#pragma unroll
  for (int j = 0; j < 16; j++) acc[j] = 0.f;

  for (int kt = 0; kt < 2; kt++) {
    {
      const float4* __restrict__ Wg = (const float4*)(W + kt * 64 * 128);
      float4* Wl = (float4*)Wsh;
      __syncthreads();
#pragma unroll
      for (int i = 0; i < 8; i++) Wl[tid + 256 * i] = Wg[tid + 256 * i];
      __syncthreads();
    }
#pragma unroll 4
    for (int kk = 0; kk < 64; kk += 4) {
      const int k = kt * 64 + kk;
      const float w0 = Wsh[(kk + 0) * 128 + c];
      const float w1 = Wsh[(kk + 1) * 128 + c];
      const float w2 = Wsh[(kk + 2) * 128 + c];
      const float w3 = Wsh[(kk + 3) * 128 + c];
#pragma unroll
      for (int j = 0; j < 16; j++) {
        const float4 a = *(const float4*)&As[(rh * 16 + j) * 128 + k];
        acc[j] = fmaf(a.x, w0, acc[j]);
        acc[j] = fmaf(a.y, w1, acc[j]);
        acc[j] = fmaf(a.z, w2, acc[j]);
        acc[j] = fmaf(a.w, w3, acc[j]);
      }
    }
  }
  float badd = 0.f;
  if (bias1) badd += bias1[c];
  if (bias2) badd += bias2[c];
#pragma unroll
  for (int j = 0; j < 16; j++)
    out[(row0 + rh * 16 + j) * 128 + c] = acc[j] + badd;
}

// ---- attention coefficients: es[n,h] = sum_c xh[n,h,c]*as[h,c]; ed likewise ----
__global__ __launch_bounds__(256) void attn_coef_k(const float* __restrict__ xh,
                                                   const float* __restrict__ as_,
                                                   const float* __restrict__ ad_,
                                                   float* __restrict__ es,
                                                   float* __restrict__ ed) {
  const int idx = blockIdx.x * 256 + threadIdx.x;
  if (idx >= NH4) return;
  const int h = idx & 3;
  const float* row = xh + (idx >> 2) * 128 + h * 32;
  float s = 0.f, d = 0.f;
#pragma unroll
  for (int c = 0; c < 32; c += 4) {
    const float4 v = *(const float4*)(row + c);
    s += v.x * as_[h * 32 + c] + v.y * as_[h * 32 + c + 1] +
         v.z * as_[h * 32 + c + 2] + v.w * as_[h * 32 + c + 3];
    d += v.x * ad_[h * 32 + c] + v.y * ad_[h * 32 + c + 1] +
         v.z * ad_[h * 32 + c + 2] + v.w * ad_[h * 32 + c + 3];
  }
  es[idx] = s;
  ed[idx] = d;
}

// ---- edge pass A: denom[d,h] += exp(leaky(es[s,h]+ed[d,h])) ----
__global__ __launch_bounds__(256) void edge_a_k(const int* __restrict__ src,
                                                const int* __restrict__ dst,
                                                const float* __restrict__ es,
                                                const float* __restrict__ ed,
                                                float* __restrict__ denom) {
  const int idx = blockIdx.x * 256 + threadIdx.x;  // over E*H
  const int e = idx >> 2, h = idx & 3;
  if (e >= NE) return;
  const int s = src[e], d = dst[e];
  float v = es[s * 4 + h] + ed[d * 4 + h];
  v = v > 0.f ? v : 0.2f * v;
  unsafeAtomicAdd(&denom[d * 4 + h], __expf(v));
}

// ---- edge pass B: acc[d,:] += xh[s,:] * alpha  (8 lanes of 4ch per head) ----
__global__ __launch_bounds__(256) void edge_b_k(const int* __restrict__ src,
                                                const int* __restrict__ dst,
                                                const float* __restrict__ es,
                                                const float* __restrict__ ed,
                                                const float* __restrict__ denom,
                                                const float* __restrict__ xh,
                                                float* __restrict__ acc) {
  const int idx = blockIdx.x * 256 + threadIdx.x;  // over E*32
  const int e = idx >> 5, ln = idx & 31;
  if (e >= NE) return;
  const int s = src[e], d = dst[e];
  const int h = ln >> 3;
  float v = es[s * 4 + h] + ed[d * 4 + h];
  v = v > 0.f ? v : 0.2f * v;
  const float alpha = __expf(v) / denom[d * 4 + h];
  const float4 m = *(const float4*)(xh + s * 128 + ln * 4);
  float* o = acc + d * 128 + ln * 4;
  unsafeAtomicAdd(o + 0, m.x * alpha);
  unsafeAtomicAdd(o + 1, m.y * alpha);
  unsafeAtomicAdd(o + 2, m.z * alpha);
  unsafeAtomicAdd(o + 3, m.w * alpha);
}

// ---- h += bias (in place, float4) ----
__global__ __launch_bounds__(256) void bias_k(float* __restrict__ h, const float* __restrict__ b) {
  const int i = blockIdx.x * 256 + threadIdx.x;  // over NHC/4
  const int c = (i * 4) & 127;
  float4 v = ((float4*)h)[i];
  const float4 bb = *(const float4*)(b + c);
  v.x += bb.x; v.y += bb.y; v.z += bb.z; v.w += bb.w;
  ((float4*)h)[i] = v;
}

// ---- hout = hin + bias ----
__global__ __launch_bounds__(256) void resid_k(float* __restrict__ hout, const float* __restrict__ hin,
                                               const float* __restrict__ b) {
  const int i = blockIdx.x * 256 + threadIdx.x;  // over NHC/4
  const int c = (i * 4) & 127;
  float4 v = ((const float4*)hin)[i];
  const float4 bb = *(const float4*)(b + c);
  v.x += bb.x; v.y += bb.y; v.z += bb.z; v.w += bb.w;
  ((float4*)hout)[i] = v;
}

// ---- final projection: out[n,32] = concat(h0,h1,h2)[n,:] @ opW + opb ----
__global__ __launch_bounds__(256) void out_proj_k(const float* __restrict__ h0,
                                                  const float* __restrict__ h1,
                                                  const float* __restrict__ h2,
                                                  const float* __restrict__ opW,
                                                  const float* __restrict__ opb,
                                                  float* __restrict__ out) {
  __shared__ float Wl[384 * 32];  // 48 KB
  const int tid = threadIdx.x;
  for (int i = tid; i < 384 * 32; i += 256) Wl[i] = opW[i];
  __syncthreads();
  const int c = tid & 31, nl = tid >> 5;
  const int n = blockIdx.x * 8 + nl;
  float a = opb[c];
  const float* r0 = h0 + n * 128;
  const float* r1 = h1 + n * 128;
  const float* r2 = h2 + n * 128;
#pragma unroll 4
  for (int k = 0; k < 128; k++) a = fmaf(r0[k], Wl[k * 32 + c], a);
#pragma unroll 4
  for (int k = 0; k < 128; k++) a = fmaf(r1[k], Wl[(128 + k) * 32 + c], a);
#pragma unroll 4
  for (int k = 0; k < 128; k++) a = fmaf(r2[k], Wl[(256 + k) * 32 + c], a);
  out[n * 32 + c] = a;
}

extern "C" void kernel_launch(void* const* d_in, const int* in_sizes, int n_in,
                              void* d_out, int out_size, void* d_ws, size_t ws_size,
                              hipStream_t stream) {
  (void)in_sizes; (void)n_in; (void)out_size; (void)ws_size;
  const float* x  = (const float*)d_in[0];
  const int*   ei = (const int*)d_in[1];
  const int*  src = ei;
  const int*  dst = ei + NE;
  const float *W0 = (const float*)d_in[2],  *as0 = (const float*)d_in[3],
              *ad0 = (const float*)d_in[4], *b0 = (const float*)d_in[5];
  const float *W1 = (const float*)d_in[6],  *as1 = (const float*)d_in[7],
              *ad1 = (const float*)d_in[8], *b1 = (const float*)d_in[9];
  const float *W2 = (const float*)d_in[10], *as2 = (const float*)d_in[11],
              *ad2 = (const float*)d_in[12], *b2 = (const float*)d_in[13];
  const float *llW = (const float*)d_in[14], *llb = (const float*)d_in[15];
  const float *opW = (const float*)d_in[16], *opb = (const float*)d_in[17];

  float* ws    = (float*)d_ws;
  float* h0f   = ws;             // NHC
  float* h1f   = h0f + NHC;      // NHC
  float* h2f   = h1f + NHC;      // NHC
  float* xh    = h2f + NHC;      // NHC
  float* es    = xh + NHC;       // NH4
  float* ed    = es + NH4;       // NH4
  float* denom = ed + NH4;       // NH4

  const dim3 blk(256);
  // ---------- layer 0 ----------
  hipMemsetAsync(h0f, 0, (size_t)NHC * 4, stream);
  hipMemsetAsync(denom, 0, (size_t)NH4 * 4, stream);
  gemm128_k<<<3125, blk, 0, stream>>>(x, W0, xh, nullptr, nullptr);
  attn_coef_k<<<1563, blk, 0, stream>>>(xh, as0, ad0, es, ed);
  edge_a_k<<<25000, blk, 0, stream>>>(src, dst, es, ed, denom);
  edge_b_k<<<200000, blk, 0, stream>>>(src, dst, es, ed, denom, xh, h0f);
  bias_k<<<12500, blk, 0, stream>>>(h0f, b0);
  // ---------- layer 1 ----------
  resid_k<<<12500, blk, 0, stream>>>(h1f, h0f, b1);  // h1 = h0 + b1, messages add on top
  hipMemsetAsync(denom, 0, (size_t)NH4 * 4, stream);
  gemm128_k<<<3125, blk, 0, stream>>>(h0f, W1, xh, nullptr, nullptr);
  attn_coef_k<<<1563, blk, 0, stream>>>(xh, as1, ad1, es, ed);
  edge_a_k<<<25000, blk, 0, stream>>>(src, dst, es, ed, denom);
  edge_b_k<<<200000, blk, 0, stream>>>(src, dst, es, ed, denom, xh, h1f);
  // ---------- layer 2 ----------
  hipMemsetAsync(denom, 0, (size_t)NH4 * 4, stream);
  gemm128_k<<<3125, blk, 0, stream>>>(h1f, llW, h2f, llb, b2);  // h2 = h1@llW + llb + b2
  gemm128_k<<<3125, blk, 0, stream>>>(h1f, W2, xh, nullptr, nullptr);
  attn_coef_k<<<1563, blk, 0, stream>>>(xh, as2, ad2, es, ed);
  edge_a_k<<<25000, blk, 0, stream>>>(src, dst, es, ed, denom);
  edge_b_k<<<200000, blk, 0, stream>>>(src, dst, es, ed, denom, xh, h2f);
  // ---------- output head ----------
  out_proj_k<<<12500, blk, 0, stream>>>(h0f, h1f, h2f, opW, opb, (float*)d_out);
}

// Round 3
// 1635.393 us; speedup vs baseline: 5.5228x; 5.5228x over previous
//
#include <hip/hip_runtime.h>
#include <hip/hip_bf16.h>

#define NN  100000
#define NE  1600000
#define NH4 400000      // N*H
#define NHC 12800000    // N*HC

// ---- GEMM: out[N,128] = A[N,128] @ W[128,128] (+ bias1 + bias2) ----
__global__ __launch_bounds__(256) void gemm128_k(const float* __restrict__ A,
                                                 const float* __restrict__ W,
                                                 float* __restrict__ out,
                                                 const float* __restrict__ bias1,
                                                 const float* __restrict__ bias2) {
  __shared__ float As[32 * 128];   // 16 KB
  __shared__ float Wsh[64 * 128];  // 32 KB
  const int tid = threadIdx.x;
  const int row0 = blockIdx.x * 32;
  {
    const float4* __restrict__ Ag = (const float4*)(A + row0 * 128);
    float4* Al = (float4*)As;
#pragma unroll
    for (int i = 0; i < 4; i++) Al[tid + 256 * i] = Ag[tid + 256 * i];
  }

  const int c = tid & 127, rh = tid >> 7;
  float acc[16];
#pragma unroll
  for (int j = 0; j < 16; j++) acc[j] = 0.f;

  for (int kt = 0; kt < 2; kt++) {
    {
      const float4* __restrict__ Wg = (const float4*)(W + kt * 64 * 128);
      float4* Wl = (float4*)Wsh;
      __syncthreads();
#pragma unroll
      for (int i = 0; i < 8; i++) Wl[tid + 256 * i] = Wg[tid + 256 * i];
      __syncthreads();
    }
#pragma unroll 4
    for (int kk = 0; kk < 64; kk += 4) {
      const int k = kt * 64 + kk;
      const float w0 = Wsh[(kk + 0) * 128 + c];
      const float w1 = Wsh[(kk + 1) * 128 + c];
      const float w2 = Wsh[(kk + 2) * 128 + c];
      const float w3 = Wsh[(kk + 3) * 128 + c];
#pragma unroll
      for (int j = 0; j < 16; j++) {
        const float4 a = *(const float4*)&As[(rh * 16 + j) * 128 + k];
        acc[j] = fmaf(a.x, w0, acc[j]);
        acc[j] = fmaf(a.y, w1, acc[j]);
        acc[j] = fmaf(a.z, w2, acc[j]);
        acc[j] = fmaf(a.w, w3, acc[j]);
      }
    }
  }
  float badd = 0.f;
  if (bias1) badd += bias1[c];
  if (bias2) badd += bias2[c];
#pragma unroll
  for (int j = 0; j < 16; j++)
    out[(row0 + rh * 16 + j) * 128 + c] = acc[j] + badd;
}

// ---- attention coefficients: es[n,h] = sum_c xh[n,h,c]*as[h,c]; ed likewise ----
__global__ __launch_bounds__(256) void attn_coef_k(const float* __restrict__ xh,
                                                   const float* __restrict__ as_,
                                                   const float* __restrict__ ad_,
                                                   float* __restrict__ es,
                                                   float* __restrict__ ed) {
  const int idx = blockIdx.x * 256 + threadIdx.x;
  if (idx >= NH4) return;
  const int h = idx & 3;
  const float* row = xh + (idx >> 2) * 128 + h * 32;
  float s = 0.f, d = 0.f;
#pragma unroll
  for (int c = 0; c < 32; c += 4) {
    const float4 v = *(const float4*)(row + c);
    s += v.x * as_[h * 32 + c] + v.y * as_[h * 32 + c + 1] +
         v.z * as_[h * 32 + c + 2] + v.w * as_[h * 32 + c + 3];
    d += v.x * ad_[h * 32 + c] + v.y * ad_[h * 32 + c + 1] +
         v.z * ad_[h * 32 + c + 2] + v.w * ad_[h * 32 + c + 3];
  }
  es[idx] = s;
  ed[idx] = d;
}

// ---- CSR build: histogram over dst ----
__global__ __launch_bounds__(256) void hist_k(const int* __restrict__ dst, int* __restrict__ counts) {
  const int i = blockIdx.x * 256 + threadIdx.x;
  if (i < NE) atomicAdd(&counts[dst[i]], 1);
}

// ---- CSR build: single-block exclusive scan of counts -> row_start, cursor ----
__global__ __launch_bounds__(1024) void scan_k(const int* __restrict__ counts,
                                               int* __restrict__ row_start,
                                               int* __restrict__ cursor) {
  __shared__ int sums[1024];
  const int t = threadIdx.x;
  const int CH = (NN + 1023) / 1024;  // 98
  const int lo = t * CH;
  const int hi = (lo + CH < NN) ? lo + CH : NN;
  int s = 0;
  for (int i = lo; i < hi && i < NN; i++) s += counts[i];
  sums[t] = s;
  __syncthreads();
  // inclusive Hillis-Steele scan
  for (int off = 1; off < 1024; off <<= 1) {
    int tmp = (t >= off) ? sums[t - off] : 0;
    __syncthreads();
    if (t >= off) sums[t] += tmp;
    __syncthreads();
  }
  int run = sums[t] - s;  // exclusive base for this chunk
  for (int i = lo; i < hi && i < NN; i++) {
    row_start[i] = run;
    cursor[i] = run;
    run += counts[i];
  }
  if (t == 1023) row_start[NN] = sums[1023];
}

// ---- CSR build: scatter edge source ids into per-dst buckets ----
__global__ __launch_bounds__(256) void scatter_k(const int* __restrict__ src,
                                                 const int* __restrict__ dst,
                                                 int* __restrict__ cursor,
                                                 int* __restrict__ csr_src) {
  const int i = blockIdx.x * 256 + threadIdx.x;
  if (i >= NE) return;
  const int pos = atomicAdd(&cursor[dst[i]], 1);
  csr_src[pos] = src[i];
}

// ---- fused GAT aggregation: one wave per dst node, no atomics ----
// out[n,:] = (sum_e w_e * xh[src_e,:]) / (sum_e w_e) [+ base[n,:]] [+ bias[:]]
__global__ __launch_bounds__(256) void gat_agg_k(const int* __restrict__ row_start,
                                                 const int* __restrict__ csr_src,
                                                 const float* __restrict__ es,
                                                 const float* __restrict__ ed,
                                                 const float* __restrict__ xh,
                                                 const float* __restrict__ base,
                                                 const float* __restrict__ bias,
                                                 float* __restrict__ out) {
  const int wid = (blockIdx.x * 256 + threadIdx.x) >> 6;  // node id
  if (wid >= NN) return;
  const int l = threadIdx.x & 63;   // lane: channels 2l, 2l+1
  const int h = l >> 4;             // head of both channels
  const float edh = ed[wid * 4 + h];
  const int beg = row_start[wid], end = row_start[wid + 1];
  float ax = 0.f, ay = 0.f, den = 0.f;
  for (int i = beg; i < end; i++) {
    const int s = csr_src[i];
    float v = es[s * 4 + h] + edh;
    v = v > 0.f ? v : 0.2f * v;
    const float w = __expf(v);
    const float2 m = *(const float2*)(xh + s * 128 + l * 2);
    den += w;
    ax = fmaf(w, m.x, ax);
    ay = fmaf(w, m.y, ay);
  }
  const float inv = den > 0.f ? 1.f / den : 0.f;
  float rx = ax * inv, ry = ay * inv;
  const int o = wid * 128 + l * 2;
  if (base) { rx += base[o]; ry += base[o + 1]; }
  if (bias) { rx += bias[l * 2]; ry += bias[l * 2 + 1]; }
  *(float2*)(out + o) = make_float2(rx, ry);
}

// ---- final projection: out[n,32] = concat(h0,h1,h2)[n,:] @ opW + opb ----
__global__ __launch_bounds__(256) void out_proj_k(const float* __restrict__ h0,
                                                  const float* __restrict__ h1,
                                                  const float* __restrict__ h2,
                                                  const float* __restrict__ opW,
                                                  const float* __restrict__ opb,
                                                  float* __restrict__ out) {
  __shared__ float Wl[384 * 32];  // 48 KB
  const int tid = threadIdx.x;
  for (int i = tid; i < 384 * 32; i += 256) Wl[i] = opW[i];
  __syncthreads();
  const int c = tid & 31, nl = tid >> 5;
  const int n = blockIdx.x * 8 + nl;
  float a = opb[c];
  const float* r0 = h0 + n * 128;
  const float* r1 = h1 + n * 128;
  const float* r2 = h2 + n * 128;
#pragma unroll 4
  for (int k = 0; k < 128; k++) a = fmaf(r0[k], Wl[k * 32 + c], a);
#pragma unroll 4
  for (int k = 0; k < 128; k++) a = fmaf(r1[k], Wl[(128 + k) * 32 + c], a);
#pragma unroll 4
  for (int k = 0; k < 128; k++) a = fmaf(r2[k], Wl[(256 + k) * 32 + c], a);
  out[n * 32 + c] = a;
}

extern "C" void kernel_launch(void* const* d_in, const int* in_sizes, int n_in,
                              void* d_out, int out_size, void* d_ws, size_t ws_size,
                              hipStream_t stream) {
  (void)in_sizes; (void)n_in; (void)out_size; (void)ws_size;
  const float* x  = (const float*)d_in[0];
  const int*   ei = (const int*)d_in[1];
  const int*  src = ei;
  const int*  dst = ei + NE;
  const float *W0 = (const float*)d_in[2],  *as0 = (const float*)d_in[3],
              *ad0 = (const float*)d_in[4], *b0 = (const float*)d_in[5];
  const float *W1 = (const float*)d_in[6],  *as1 = (const float*)d_in[7],
              *ad1 = (const float*)d_in[8], *b1 = (const float*)d_in[9];
  const float *W2 = (const float*)d_in[10], *as2 = (const float*)d_in[11],
              *ad2 = (const float*)d_in[12], *b2 = (const float*)d_in[13];
  const float *llW = (const float*)d_in[14], *llb = (const float*)d_in[15];
  const float *opW = (const float*)d_in[16], *opb = (const float*)d_in[17];

  float* ws    = (float*)d_ws;
  float* h0f   = ws;             // NHC
  float* h1f   = h0f + NHC;      // NHC
  float* h2f   = h1f + NHC;      // NHC
  float* xh    = h2f + NHC;      // NHC
  float* es    = xh + NHC;       // NH4
  float* ed    = es + NH4;       // NH4
  int* row_start = (int*)(ed + NH4);      // NN+1
  int* cursor    = row_start + NN + 1;    // NN
  int* counts    = cursor + NN;           // NN
  int* csr_src   = counts + NN;           // NE

  const dim3 blk(256);
  // ---------- CSR build (edges shared by all 3 layers) ----------
  hipMemsetAsync(counts, 0, (size_t)NN * 4, stream);
  hist_k<<<6250, blk, 0, stream>>>(dst, counts);
  scan_k<<<1, 1024, 0, stream>>>(counts, row_start, cursor);
  scatter_k<<<6250, blk, 0, stream>>>(src, dst, cursor, csr_src);
  // ---------- layer 0 ----------
  gemm128_k<<<3125, blk, 0, stream>>>(x, W0, xh, nullptr, nullptr);
  attn_coef_k<<<1563, blk, 0, stream>>>(xh, as0, ad0, es, ed);
  gat_agg_k<<<25000, blk, 0, stream>>>(row_start, csr_src, es, ed, xh, nullptr, b0, h0f);
  // ---------- layer 1 ----------
  gemm128_k<<<3125, blk, 0, stream>>>(h0f, W1, xh, nullptr, nullptr);
  attn_coef_k<<<1563, blk, 0, stream>>>(xh, as1, ad1, es, ed);
  gat_agg_k<<<25000, blk, 0, stream>>>(row_start, csr_src, es, ed, xh, h0f, b1, h1f);
  // ---------- layer 2 ----------
  gemm128_k<<<3125, blk, 0, stream>>>(h1f, llW, h2f, llb, b2);  // h2 base = h1@llW + llb + b2
  gemm128_k<<<3125, blk, 0, stream>>>(h1f, W2, xh, nullptr, nullptr);
  attn_coef_k<<<1563, blk, 0, stream>>>(xh, as2, ad2, es, ed);
  gat_agg_k<<<25000, blk, 0, stream>>>(row_start, csr_src, es, ed, xh, h2f, nullptr, h2f);
  // ---------- output head ----------
  out_proj_k<<<12500, blk, 0, stream>>>(h0f, h1f, h2f, opW, opb, (float*)d_out);
}

// Round 4
// 1323.436 us; speedup vs baseline: 6.8247x; 1.2357x over previous
//
#include <hip/hip_runtime.h>
#include <hip/hip_bf16.h>

#define NN  100000
#define NE  1600000
#define NH4 400000      // N*H
#define NHC 12800000    // N*HC

// ---- GEMM: out[N,128] = A[N,128] @ W[128,128] (+ bias1 + bias2) ----
__global__ __launch_bounds__(256) void gemm128_k(const float* __restrict__ A,
                                                 const float* __restrict__ W,
                                                 float* __restrict__ out,
                                                 const float* __restrict__ bias1,
                                                 const float* __restrict__ bias2) {
  __shared__ float As[32 * 128];   // 16 KB
  __shared__ float Wsh[64 * 128];  // 32 KB
  const int tid = threadIdx.x;
  const int row0 = blockIdx.x * 32;
  {
    const float4* __restrict__ Ag = (const float4*)(A + row0 * 128);
    float4* Al = (float4*)As;
#pragma unroll
    for (int i = 0; i < 4; i++) Al[tid + 256 * i] = Ag[tid + 256 * i];
  }

  const int c = tid & 127, rh = tid >> 7;
  float acc[16];
#pragma unroll
  for (int j = 0; j < 16; j++) acc[j] = 0.f;

  for (int kt = 0; kt < 2; kt++) {
    {
      const float4* __restrict__ Wg = (const float4*)(W + kt * 64 * 128);
      float4* Wl = (float4*)Wsh;
      __syncthreads();
#pragma unroll
      for (int i = 0; i < 8; i++) Wl[tid + 256 * i] = Wg[tid + 256 * i];
      __syncthreads();
    }
#pragma unroll 4
    for (int kk = 0; kk < 64; kk += 4) {
      const int k = kt * 64 + kk;
      const float w0 = Wsh[(kk + 0) * 128 + c];
      const float w1 = Wsh[(kk + 1) * 128 + c];
      const float w2 = Wsh[(kk + 2) * 128 + c];
      const float w3 = Wsh[(kk + 3) * 128 + c];
#pragma unroll
      for (int j = 0; j < 16; j++) {
        const float4 a = *(const float4*)&As[(rh * 16 + j) * 128 + k];
        acc[j] = fmaf(a.x, w0, acc[j]);
        acc[j] = fmaf(a.y, w1, acc[j]);
        acc[j] = fmaf(a.z, w2, acc[j]);
        acc[j] = fmaf(a.w, w3, acc[j]);
      }
    }
  }
  float badd = 0.f;
  if (bias1) badd += bias1[c];
  if (bias2) badd += bias2[c];
#pragma unroll
  for (int j = 0; j < 16; j++)
    out[(row0 + rh * 16 + j) * 128 + c] = acc[j] + badd;
}

// ---- attention coefficients ----
__global__ __launch_bounds__(256) void attn_coef_k(const float* __restrict__ xh,
                                                   const float* __restrict__ as_,
                                                   const float* __restrict__ ad_,
                                                   float* __restrict__ es,
                                                   float* __restrict__ ed) {
  const int idx = blockIdx.x * 256 + threadIdx.x;
  if (idx >= NH4) return;
  const int h = idx & 3;
  const float* row = xh + (idx >> 2) * 128 + h * 32;
  float s = 0.f, d = 0.f;
#pragma unroll
  for (int c = 0; c < 32; c += 4) {
    const float4 v = *(const float4*)(row + c);
    s += v.x * as_[h * 32 + c] + v.y * as_[h * 32 + c + 1] +
         v.z * as_[h * 32 + c + 2] + v.w * as_[h * 32 + c + 3];
    d += v.x * ad_[h * 32 + c] + v.y * ad_[h * 32 + c + 1] +
         v.z * ad_[h * 32 + c + 2] + v.w * ad_[h * 32 + c + 3];
  }
  es[idx] = s;
  ed[idx] = d;
}

// ---- CSR build ----
__global__ __launch_bounds__(256) void hist_k(const int* __restrict__ dst, int* __restrict__ counts) {
  const int i = blockIdx.x * 256 + threadIdx.x;
  if (i < NE) atomicAdd(&counts[dst[i]], 1);
}

__global__ __launch_bounds__(1024) void scan_k(const int* __restrict__ counts,
                                               int* __restrict__ row_start,
                                               int* __restrict__ cursor) {
  __shared__ int sums[1024];
  const int t = threadIdx.x;
  const int CH = (NN + 1023) / 1024;  // 98
  const int lo = t * CH;
  const int hi = (lo + CH < NN) ? lo + CH : NN;
  int s = 0;
  for (int i = lo; i < hi && i < NN; i++) s += counts[i];
  sums[t] = s;
  __syncthreads();
  for (int off = 1; off < 1024; off <<= 1) {
    int tmp = (t >= off) ? sums[t - off] : 0;
    __syncthreads();
    if (t >= off) sums[t] += tmp;
    __syncthreads();
  }
  int run = sums[t] - s;
  for (int i = lo; i < hi && i < NN; i++) {
    row_start[i] = run;
    cursor[i] = run;
    run += counts[i];
  }
  if (t == 1023) row_start[NN] = sums[1023];
}

__global__ __launch_bounds__(256) void scatter_k(const int* __restrict__ src,
                                                 const int* __restrict__ dst,
                                                 int* __restrict__ cursor,
                                                 int* __restrict__ csr_src) {
  const int i = blockIdx.x * 256 + threadIdx.x;
  if (i >= NE) return;
  const int pos = atomicAdd(&cursor[dst[i]], 1);
  csr_src[pos] = src[i];
}

// ---- fused GAT aggregation: one wave per dst node, 4-way ILP, no atomics ----
__global__ __launch_bounds__(256) void gat_agg_k(const int* __restrict__ row_start,
                                                 const int* __restrict__ csr_src,
                                                 const float* __restrict__ es,
                                                 const float* __restrict__ ed,
                                                 const float* __restrict__ xh,
                                                 const float* __restrict__ base,
                                                 const float* __restrict__ bias,
                                                 float* __restrict__ out) {
  const int wid = (blockIdx.x * 256 + threadIdx.x) >> 6;  // node id
  if (wid >= NN) return;
  const int l = threadIdx.x & 63;   // lane: channels 2l, 2l+1
  const int h = l >> 4;             // head of both channels
  const float edh = ed[wid * 4 + h];
  const int beg = row_start[wid], end = row_start[wid + 1];
  float ax = 0.f, ay = 0.f, den = 0.f;
  int i = beg;
  for (; i + 4 <= end; i += 4) {
    const int s0 = csr_src[i], s1 = csr_src[i + 1];
    const int s2 = csr_src[i + 2], s3 = csr_src[i + 3];
    const float e0 = es[s0 * 4 + h], e1 = es[s1 * 4 + h];
    const float e2 = es[s2 * 4 + h], e3 = es[s3 * 4 + h];
    const float2 m0 = *(const float2*)(xh + (size_t)s0 * 128 + l * 2);
    const float2 m1 = *(const float2*)(xh + (size_t)s1 * 128 + l * 2);
    const float2 m2 = *(const float2*)(xh + (size_t)s2 * 128 + l * 2);
    const float2 m3 = *(const float2*)(xh + (size_t)s3 * 128 + l * 2);
    float v0 = e0 + edh; v0 = v0 > 0.f ? v0 : 0.2f * v0;
    float v1 = e1 + edh; v1 = v1 > 0.f ? v1 : 0.2f * v1;
    float v2 = e2 + edh; v2 = v2 > 0.f ? v2 : 0.2f * v2;
    float v3 = e3 + edh; v3 = v3 > 0.f ? v3 : 0.2f * v3;
    const float w0 = __expf(v0), w1 = __expf(v1), w2 = __expf(v2), w3 = __expf(v3);
    den += (w0 + w1) + (w2 + w3);
    ax = fmaf(w0, m0.x, ax); ay = fmaf(w0, m0.y, ay);
    ax = fmaf(w1, m1.x, ax); ay = fmaf(w1, m1.y, ay);
    ax = fmaf(w2, m2.x, ax); ay = fmaf(w2, m2.y, ay);
    ax = fmaf(w3, m3.x, ax); ay = fmaf(w3, m3.y, ay);
  }
  for (; i < end; i++) {
    const int s = csr_src[i];
    float v = es[s * 4 + h] + edh;
    v = v > 0.f ? v : 0.2f * v;
    const float w = __expf(v);
    const float2 m = *(const float2*)(xh + (size_t)s * 128 + l * 2);
    den += w;
    ax = fmaf(w, m.x, ax);
    ay = fmaf(w, m.y, ay);
  }
  const float inv = den > 0.f ? 1.f / den : 0.f;
  float rx = ax * inv, ry = ay * inv;
  const int o = wid * 128 + l * 2;
  if (base) { rx += base[o]; ry += base[o + 1]; }
  if (bias) { rx += bias[l * 2]; ry += bias[l * 2 + 1]; }
  *(float2*)(out + o) = make_float2(rx, ry);
}

// ---- final projection: one thread per node, 32 accumulators, w via scalar loads ----
__global__ __launch_bounds__(256) void out_proj_k(const float* __restrict__ h0,
                                                  const float* __restrict__ h1,
                                                  const float* __restrict__ h2,
                                                  const float* __restrict__ opW,
                                                  const float* __restrict__ opb,
                                                  float* __restrict__ out) {
  const int n = blockIdx.x * 256 + threadIdx.x;
  if (n >= NN) return;
  float acc[32];
#pragma unroll
  for (int c = 0; c < 32; c++) acc[c] = opb[c];  // uniform -> scalar loads

  const float4* __restrict__ r0 = (const float4*)(h0 + (size_t)n * 128);
  const float4* __restrict__ r1 = (const float4*)(h1 + (size_t)n * 128);
  const float4* __restrict__ r2 = (const float4*)(h2 + (size_t)n * 128);

#define SEG_STEP(a, kbase)                                                    \
  {                                                                           \
    const float* __restrict__ wr = opW + (kbase) * 32;                        \
    _Pragma("unroll") for (int c = 0; c < 32; c++)                            \
        acc[c] = fmaf((a).x, wr[c], acc[c]);                                  \
    _Pragma("unroll") for (int c = 0; c < 32; c++)                            \
        acc[c] = fmaf((a).y, wr[32 + c], acc[c]);                             \
    _Pragma("unroll") for (int c = 0; c < 32; c++)                            \
        acc[c] = fmaf((a).z, wr[64 + c], acc[c]);                             \
    _Pragma("unroll") for (int c = 0; c < 32; c++)                            \
        acc[c] = fmaf((a).w, wr[96 + c], acc[c]);                             \
  }

  for (int k4 = 0; k4 < 32; k4++) {
    const float4 a = r0[k4];
    SEG_STEP(a, k4 * 4);
  }
  for (int k4 = 0; k4 < 32; k4++) {
    const float4 a = r1[k4];
    SEG_STEP(a, 128 + k4 * 4);
  }
  for (int k4 = 0; k4 < 32; k4++) {
    const float4 a = r2[k4];
    SEG_STEP(a, 256 + k4 * 4);
  }
#undef SEG_STEP

  float* __restrict__ o = out + (size_t)n * 32;
#pragma unroll
  for (int c = 0; c < 32; c += 4)
    *(float4*)(o + c) = make_float4(acc[c], acc[c + 1], acc[c + 2], acc[c + 3]);
}

extern "C" void kernel_launch(void* const* d_in, const int* in_sizes, int n_in,
                              void* d_out, int out_size, void* d_ws, size_t ws_size,
                              hipStream_t stream) {
  (void)in_sizes; (void)n_in; (void)out_size; (void)ws_size;
  const float* x  = (const float*)d_in[0];
  const int*   ei = (const int*)d_in[1];
  const int*  src = ei;
  const int*  dst = ei + NE;
  const float *W0 = (const float*)d_in[2],  *as0 = (const float*)d_in[3],
              *ad0 = (const float*)d_in[4], *b0 = (const float*)d_in[5];
  const float *W1 = (const float*)d_in[6],  *as1 = (const float*)d_in[7],
              *ad1 = (const float*)d_in[8], *b1 = (const float*)d_in[9];
  const float *W2 = (const float*)d_in[10], *as2 = (const float*)d_in[11],
              *ad2 = (const float*)d_in[12], *b2 = (const float*)d_in[13];
  const float *llW = (const float*)d_in[14], *llb = (const float*)d_in[15];
  const float *opW = (const float*)d_in[16], *opb = (const float*)d_in[17];

  float* ws    = (float*)d_ws;
  float* h0f   = ws;             // NHC
  float* h1f   = h0f + NHC;      // NHC
  float* h2f   = h1f + NHC;      // NHC
  float* xh    = h2f + NHC;      // NHC
  float* es    = xh + NHC;       // NH4
  float* ed    = es + NH4;       // NH4
  int* row_start = (int*)(ed + NH4);      // NN+1
  int* cursor    = row_start + NN + 1;    // NN
  int* counts    = cursor + NN;           // NN
  int* csr_src   = counts + NN;           // NE

  const dim3 blk(256);
  // ---------- CSR build (edges shared by all 3 layers) ----------
  hipMemsetAsync(counts, 0, (size_t)NN * 4, stream);
  hist_k<<<6250, blk, 0, stream>>>(dst, counts);
  scan_k<<<1, 1024, 0, stream>>>(counts, row_start, cursor);
  scatter_k<<<6250, blk, 0, stream>>>(src, dst, cursor, csr_src);
  // ---------- layer 0 ----------
  gemm128_k<<<3125, blk, 0, stream>>>(x, W0, xh, nullptr, nullptr);
  attn_coef_k<<<1563, blk, 0, stream>>>(xh, as0, ad0, es, ed);
  gat_agg_k<<<25000, blk, 0, stream>>>(row_start, csr_src, es, ed, xh, nullptr, b0, h0f);
  // ---------- layer 1 ----------
  gemm128_k<<<3125, blk, 0, stream>>>(h0f, W1, xh, nullptr, nullptr);
  attn_coef_k<<<1563, blk, 0, stream>>>(xh, as1, ad1, es, ed);
  gat_agg_k<<<25000, blk, 0, stream>>>(row_start, csr_src, es, ed, xh, h0f, b1, h1f);
  // ---------- layer 2 ----------
  gemm128_k<<<3125, blk, 0, stream>>>(h1f, llW, h2f, llb, b2);  // h2 base = h1@llW + llb + b2
  gemm128_k<<<3125, blk, 0, stream>>>(h1f, W2, xh, nullptr, nullptr);
  attn_coef_k<<<1563, blk, 0, stream>>>(xh, as2, ad2, es, ed);
  gat_agg_k<<<25000, blk, 0, stream>>>(row_start, csr_src, es, ed, xh, h2f, nullptr, h2f);
  // ---------- output head ----------
  out_proj_k<<<391, blk, 0, stream>>>(h0f, h1f, h2f, opW, opb, (float*)d_out);
}

// Round 5
// 1091.332 us; speedup vs baseline: 8.2761x; 1.2127x over previous
//
#include <hip/hip_runtime.h>
#include <hip/hip_bf16.h>

#define NN  100000
#define NE  1600000
#define NH4 400000      // N*H
#define NHC 12800000    // N*HC
#define NBLK 391        // ceil(NN/256)

// ---- GEMM: out[N,128] = A[N,128] @ W[128,128] (+ bias1 + bias2) ----
__global__ __launch_bounds__(256) void gemm128_k(const float* __restrict__ A,
                                                 const float* __restrict__ W,
                                                 float* __restrict__ out,
                                                 const float* __restrict__ bias1,
                                                 const float* __restrict__ bias2) {
  __shared__ float As[32 * 128];   // 16 KB
  __shared__ float Wsh[64 * 128];  // 32 KB
  const int tid = threadIdx.x;
  const int row0 = blockIdx.x * 32;
  {
    const float4* __restrict__ Ag = (const float4*)(A + row0 * 128);
    float4* Al = (float4*)As;
#pragma unroll
    for (int i = 0; i < 4; i++) Al[tid + 256 * i] = Ag[tid + 256 * i];
  }

  const int c = tid & 127, rh = tid >> 7;
  float acc[16];
#pragma unroll
  for (int j = 0; j < 16; j++) acc[j] = 0.f;

  for (int kt = 0; kt < 2; kt++) {
    {
      const float4* __restrict__ Wg = (const float4*)(W + kt * 64 * 128);
      float4* Wl = (float4*)Wsh;
      __syncthreads();
#pragma unroll
      for (int i = 0; i < 8; i++) Wl[tid + 256 * i] = Wg[tid + 256 * i];
      __syncthreads();
    }
#pragma unroll 4
    for (int kk = 0; kk < 64; kk += 4) {
      const int k = kt * 64 + kk;
      const float w0 = Wsh[(kk + 0) * 128 + c];
      const float w1 = Wsh[(kk + 1) * 128 + c];
      const float w2 = Wsh[(kk + 2) * 128 + c];
      const float w3 = Wsh[(kk + 3) * 128 + c];
#pragma unroll
      for (int j = 0; j < 16; j++) {
        const float4 a = *(const float4*)&As[(rh * 16 + j) * 128 + k];
        acc[j] = fmaf(a.x, w0, acc[j]);
        acc[j] = fmaf(a.y, w1, acc[j]);
        acc[j] = fmaf(a.z, w2, acc[j]);
        acc[j] = fmaf(a.w, w3, acc[j]);
      }
    }
  }
  float badd = 0.f;
  if (bias1) badd += bias1[c];
  if (bias2) badd += bias2[c];
#pragma unroll
  for (int j = 0; j < 16; j++)
    out[(row0 + rh * 16 + j) * 128 + c] = acc[j] + badd;
}

// ---- attention coefficients ----
__global__ __launch_bounds__(256) void attn_coef_k(const float* __restrict__ xh,
                                                   const float* __restrict__ as_,
                                                   const float* __restrict__ ad_,
                                                   float* __restrict__ es,
                                                   float* __restrict__ ed) {
  const int idx = blockIdx.x * 256 + threadIdx.x;
  if (idx >= NH4) return;
  const int h = idx & 3;
  const float* row = xh + (idx >> 2) * 128 + h * 32;
  float s = 0.f, d = 0.f;
#pragma unroll
  for (int c = 0; c < 32; c += 4) {
    const float4 v = *(const float4*)(row + c);
    s += v.x * as_[h * 32 + c] + v.y * as_[h * 32 + c + 1] +
         v.z * as_[h * 32 + c + 2] + v.w * as_[h * 32 + c + 3];
    d += v.x * ad_[h * 32 + c] + v.y * ad_[h * 32 + c + 1] +
         v.z * ad_[h * 32 + c + 2] + v.w * ad_[h * 32 + c + 3];
  }
  es[idx] = s;
  ed[idx] = d;
}

// ---- CSR build: histogram ----
__global__ __launch_bounds__(256) void hist_k(const int* __restrict__ dst, int* __restrict__ counts) {
  const int i = blockIdx.x * 256 + threadIdx.x;
  if (i < NE) atomicAdd(&counts[dst[i]], 1);
}

// ---- two-level scan: per-block exclusive scan + block sums ----
__global__ __launch_bounds__(256) void scan_blk_k(const int* __restrict__ counts,
                                                  int* __restrict__ row_start,
                                                  int* __restrict__ blocksum) {
  __shared__ int sm[256];
  const int t = threadIdx.x;
  const int i = blockIdx.x * 256 + t;
  const int c = (i < NN) ? counts[i] : 0;
  sm[t] = c;
  __syncthreads();
#pragma unroll
  for (int off = 1; off < 256; off <<= 1) {
    const int v = (t >= off) ? sm[t - off] : 0;
    __syncthreads();
    sm[t] += v;
    __syncthreads();
  }
  if (i < NN) row_start[i] = sm[t] - c;  // exclusive, pre-offset
  if (t == 255) blocksum[blockIdx.x] = sm[255];
}

__global__ __launch_bounds__(512) void scan_top_k(const int* __restrict__ blocksum,
                                                  int* __restrict__ blockoff) {
  __shared__ int sm[512];
  const int t = threadIdx.x;
  const int c = (t < NBLK) ? blocksum[t] : 0;
  sm[t] = c;
  __syncthreads();
#pragma unroll
  for (int off = 1; off < 512; off <<= 1) {
    const int v = (t >= off) ? sm[t - off] : 0;
    __syncthreads();
    sm[t] += v;
    __syncthreads();
  }
  if (t < NBLK) blockoff[t] = sm[t] - c;  // exclusive
}

__global__ __launch_bounds__(256) void scan_fix_k(int* __restrict__ row_start,
                                                  const int* __restrict__ blockoff,
                                                  int* __restrict__ cursor) {
  const int i = blockIdx.x * 256 + threadIdx.x;
  if (i < NN) {
    const int v = row_start[i] + blockoff[blockIdx.x];
    row_start[i] = v;
    cursor[i] = v;
  }
  if (i == 0) row_start[NN] = NE;
}

__global__ __launch_bounds__(256) void scatter_k(const int* __restrict__ src,
                                                 const int* __restrict__ dst,
                                                 int* __restrict__ cursor,
                                                 int* __restrict__ csr_src) {
  const int i = blockIdx.x * 256 + threadIdx.x;
  if (i >= NE) return;
  const int pos = atomicAdd(&cursor[dst[i]], 1);
  csr_src[pos] = src[i];
}

// ---- fused GAT aggregation: one wave per dst node, 8-way ILP, no atomics ----
#define EDGE_BODY(sv)                                                      \
  {                                                                        \
    const int s_ = (sv);                                                   \
    float v_ = es[s_ * 4 + h] + edh;                                       \
    v_ = v_ > 0.f ? v_ : 0.2f * v_;                                        \
    const float w_ = __expf(v_);                                           \
    const float2 m_ = *(const float2*)(xh + (size_t)s_ * 128 + l * 2);     \
    den += w_;                                                             \
    ax = fmaf(w_, m_.x, ax);                                               \
    ay = fmaf(w_, m_.y, ay);                                               \
  }

__global__ __launch_bounds__(256) void gat_agg_k(const int* __restrict__ row_start,
                                                 const int* __restrict__ csr_src,
                                                 const float* __restrict__ es,
                                                 const float* __restrict__ ed,
                                                 const float* __restrict__ xh,
                                                 const float* __restrict__ base,
                                                 const float* __restrict__ bias,
                                                 float* __restrict__ out) {
  const int wid = (blockIdx.x * 256 + threadIdx.x) >> 6;  // node id
  if (wid >= NN) return;
  const int l = threadIdx.x & 63;   // lane: channels 2l, 2l+1
  const int h = l >> 4;             // head of both channels
  const float edh = ed[wid * 4 + h];
  const int beg = row_start[wid], end = row_start[wid + 1];
  float ax = 0.f, ay = 0.f, den = 0.f;
  int i = beg;
  for (; i + 8 <= end; i += 8) {
    const int s0 = csr_src[i],     s1 = csr_src[i + 1];
    const int s2 = csr_src[i + 2], s3 = csr_src[i + 3];
    const int s4 = csr_src[i + 4], s5 = csr_src[i + 5];
    const int s6 = csr_src[i + 6], s7 = csr_src[i + 7];
    EDGE_BODY(s0) EDGE_BODY(s1) EDGE_BODY(s2) EDGE_BODY(s3)
    EDGE_BODY(s4) EDGE_BODY(s5) EDGE_BODY(s6) EDGE_BODY(s7)
  }
  for (; i + 4 <= end; i += 4) {
    const int s0 = csr_src[i],     s1 = csr_src[i + 1];
    const int s2 = csr_src[i + 2], s3 = csr_src[i + 3];
    EDGE_BODY(s0) EDGE_BODY(s1) EDGE_BODY(s2) EDGE_BODY(s3)
  }
  for (; i < end; i++) EDGE_BODY(csr_src[i]);

  const float inv = den > 0.f ? 1.f / den : 0.f;
  float rx = ax * inv, ry = ay * inv;
  const int o = wid * 128 + l * 2;
  if (base) { rx += base[o]; ry += base[o + 1]; }
  if (bias) { rx += bias[l * 2]; ry += bias[l * 2 + 1]; }
  *(float2*)(out + o) = make_float2(rx, ry);
}

// ---- final projection: one thread per node, 32 accumulators, w via scalar loads ----
__global__ __launch_bounds__(256) void out_proj_k(const float* __restrict__ h0,
                                                  const float* __restrict__ h1,
                                                  const float* __restrict__ h2,
                                                  const float* __restrict__ opW,
                                                  const float* __restrict__ opb,
                                                  float* __restrict__ out) {
  const int n = blockIdx.x * 256 + threadIdx.x;
  if (n >= NN) return;
  float acc[32];
#pragma unroll
  for (int c = 0; c < 32; c++) acc[c] = opb[c];  // uniform -> scalar loads

  const float4* __restrict__ r0 = (const float4*)(h0 + (size_t)n * 128);
  const float4* __restrict__ r1 = (const float4*)(h1 + (size_t)n * 128);
  const float4* __restrict__ r2 = (const float4*)(h2 + (size_t)n * 128);

#define SEG_STEP(a, kbase)                                                    \
  {                                                                           \
    const float* __restrict__ wr = opW + (kbase) * 32;                        \
    _Pragma("unroll") for (int c = 0; c < 32; c++)                            \
        acc[c] = fmaf((a).x, wr[c], acc[c]);                                  \
    _Pragma("unroll") for (int c = 0; c < 32; c++)                            \
        acc[c] = fmaf((a).y, wr[32 + c], acc[c]);                             \
    _Pragma("unroll") for (int c = 0; c < 32; c++)                            \
        acc[c] = fmaf((a).z, wr[64 + c], acc[c]);                             \
    _Pragma("unroll") for (int c = 0; c < 32; c++)                            \
        acc[c] = fmaf((a).w, wr[96 + c], acc[c]);                             \
  }

  for (int k4 = 0; k4 < 32; k4++) {
    const float4 a = r0[k4];
    SEG_STEP(a, k4 * 4);
  }
  for (int k4 = 0; k4 < 32; k4++) {
    const float4 a = r1[k4];
    SEG_STEP(a, 128 + k4 * 4);
  }
  for (int k4 = 0; k4 < 32; k4++) {
    const float4 a = r2[k4];
    SEG_STEP(a, 256 + k4 * 4);
  }
#undef SEG_STEP

  float* __restrict__ o = out + (size_t)n * 32;
#pragma unroll
  for (int c = 0; c < 32; c += 4)
    *(float4*)(o + c) = make_float4(acc[c], acc[c + 1], acc[c + 2], acc[c + 3]);
}

extern "C" void kernel_launch(void* const* d_in, const int* in_sizes, int n_in,
                              void* d_out, int out_size, void* d_ws, size_t ws_size,
                              hipStream_t stream) {
  (void)in_sizes; (void)n_in; (void)out_size; (void)ws_size;
  const float* x  = (const float*)d_in[0];
  const int*   ei = (const int*)d_in[1];
  const int*  src = ei;
  const int*  dst = ei + NE;
  const float *W0 = (const float*)d_in[2],  *as0 = (const float*)d_in[3],
              *ad0 = (const float*)d_in[4], *b0 = (const float*)d_in[5];
  const float *W1 = (const float*)d_in[6],  *as1 = (const float*)d_in[7],
              *ad1 = (const float*)d_in[8], *b1 = (const float*)d_in[9];
  const float *W2 = (const float*)d_in[10], *as2 = (const float*)d_in[11],
              *ad2 = (const float*)d_in[12], *b2 = (const float*)d_in[13];
  const float *llW = (const float*)d_in[14], *llb = (const float*)d_in[15];
  const float *opW = (const float*)d_in[16], *opb = (const float*)d_in[17];

  float* ws    = (float*)d_ws;
  float* h0f   = ws;             // NHC
  float* h1f   = h0f + NHC;      // NHC
  float* h2f   = h1f + NHC;      // NHC
  float* xh    = h2f + NHC;      // NHC
  float* es    = xh + NHC;       // NH4
  float* ed    = es + NH4;       // NH4
  int* row_start = (int*)(ed + NH4);      // NN+1
  int* cursor    = row_start + NN + 1;    // NN
  int* counts    = cursor + NN;           // NN
  int* csr_src   = counts + NN;           // NE
  int* blocksum  = csr_src + NE;          // NBLK
  int* blockoff  = blocksum + NBLK;       // NBLK

  const dim3 blk(256);
  // ---------- CSR build (edges shared by all 3 layers) ----------
  hipMemsetAsync(counts, 0, (size_t)NN * 4, stream);
  hist_k<<<6250, blk, 0, stream>>>(dst, counts);
  scan_blk_k<<<NBLK, blk, 0, stream>>>(counts, row_start, blocksum);
  scan_top_k<<<1, 512, 0, stream>>>(blocksum, blockoff);
  scan_fix_k<<<NBLK, blk, 0, stream>>>(row_start, blockoff, cursor);
  scatter_k<<<6250, blk, 0, stream>>>(src, dst, cursor, csr_src);
  // ---------- layer 0 ----------
  gemm128_k<<<3125, blk, 0, stream>>>(x, W0, xh, nullptr, nullptr);
  attn_coef_k<<<1563, blk, 0, stream>>>(xh, as0, ad0, es, ed);
  gat_agg_k<<<25000, blk, 0, stream>>>(row_start, csr_src, es, ed, xh, nullptr, b0, h0f);
  // ---------- layer 1 ----------
  gemm128_k<<<3125, blk, 0, stream>>>(h0f, W1, xh, nullptr, nullptr);
  attn_coef_k<<<1563, blk, 0, stream>>>(xh, as1, ad1, es, ed);
  gat_agg_k<<<25000, blk, 0, stream>>>(row_start, csr_src, es, ed, xh, h0f, b1, h1f);
  // ---------- layer 2 ----------
  gemm128_k<<<3125, blk, 0, stream>>>(h1f, llW, h2f, llb, b2);  // h2 base = h1@llW + llb + b2
  gemm128_k<<<3125, blk, 0, stream>>>(h1f, W2, xh, nullptr, nullptr);
  attn_coef_k<<<1563, blk, 0, stream>>>(xh, as2, ad2, es, ed);
  gat_agg_k<<<25000, blk, 0, stream>>>(row_start, csr_src, es, ed, xh, h2f, nullptr, h2f);
  // ---------- output head ----------
  out_proj_k<<<391, blk, 0, stream>>>(h0f, h1f, h2f, opW, opb, (float*)d_out);
}

// Round 6
// 916.300 us; speedup vs baseline: 9.8571x; 1.1910x over previous
//
#include <hip/hip_runtime.h>
#include <hip/hip_bf16.h>

#define NN  100000
#define NE  1600000
#define NH4 400000      // N*H
#define NHC 12800000    // N*HC
#define NBLK 391        // ceil(NN/256)

__device__ __forceinline__ ushort f2bf(float f) {  // RNE f32 -> bf16 bits
  uint u = __float_as_uint(f);
  u += 0x7fff + ((u >> 16) & 1);
  return (ushort)(u >> 16);
}

// ---- GEMM: out[N,128] = A[N,128] @ W[128,128] (+ bias1 + bias2) ----
// BF16OUT: write bf16 (for xh, the gather target); else f32.
template <bool BF16OUT>
__global__ __launch_bounds__(256) void gemm128_k(const float* __restrict__ A,
                                                 const float* __restrict__ W,
                                                 void* __restrict__ outv,
                                                 const float* __restrict__ bias1,
                                                 const float* __restrict__ bias2) {
  __shared__ float As[32 * 128];   // 16 KB
  __shared__ float Wsh[64 * 128];  // 32 KB
  const int tid = threadIdx.x;
  const int row0 = blockIdx.x * 32;
  {
    const float4* __restrict__ Ag = (const float4*)(A + row0 * 128);
    float4* Al = (float4*)As;
#pragma unroll
    for (int i = 0; i < 4; i++) Al[tid + 256 * i] = Ag[tid + 256 * i];
  }

  const int c = tid & 127, rh = tid >> 7;
  float acc[16];
#pragma unroll
  for (int j = 0; j < 16; j++) acc[j] = 0.f;

  for (int kt = 0; kt < 2; kt++) {
    {
      const float4* __restrict__ Wg = (const float4*)(W + kt * 64 * 128);
      float4* Wl = (float4*)Wsh;
      __syncthreads();
#pragma unroll
      for (int i = 0; i < 8; i++) Wl[tid + 256 * i] = Wg[tid + 256 * i];
      __syncthreads();
    }
#pragma unroll 4
    for (int kk = 0; kk < 64; kk += 4) {
      const int k = kt * 64 + kk;
      const float w0 = Wsh[(kk + 0) * 128 + c];
      const float w1 = Wsh[(kk + 1) * 128 + c];
      const float w2 = Wsh[(kk + 2) * 128 + c];
      const float w3 = Wsh[(kk + 3) * 128 + c];
#pragma unroll
      for (int j = 0; j < 16; j++) {
        const float4 a = *(const float4*)&As[(rh * 16 + j) * 128 + k];
        acc[j] = fmaf(a.x, w0, acc[j]);
        acc[j] = fmaf(a.y, w1, acc[j]);
        acc[j] = fmaf(a.z, w2, acc[j]);
        acc[j] = fmaf(a.w, w3, acc[j]);
      }
    }
  }
  float badd = 0.f;
  if (bias1) badd += bias1[c];
  if (bias2) badd += bias2[c];
  if constexpr (BF16OUT) {
    ushort* out = (ushort*)outv;
#pragma unroll
    for (int j = 0; j < 16; j++)
      out[(size_t)(row0 + rh * 16 + j) * 128 + c] = f2bf(acc[j] + badd);
  } else {
    float* out = (float*)outv;
#pragma unroll
    for (int j = 0; j < 16; j++)
      out[(size_t)(row0 + rh * 16 + j) * 128 + c] = acc[j] + badd;
  }
}

// ---- attention coefficients from bf16 xh ----
__global__ __launch_bounds__(256) void attn_coef_k(const uint* __restrict__ xbf,
                                                   const float* __restrict__ as_,
                                                   const float* __restrict__ ad_,
                                                   float* __restrict__ es,
                                                   float* __restrict__ ed) {
  const int idx = blockIdx.x * 256 + threadIdx.x;
  if (idx >= NH4) return;
  const int h = idx & 3;
  const int ab = h * 32;
  const uint* row = xbf + (size_t)(idx >> 2) * 64 + h * 16;
  float s = 0.f, d = 0.f;
#pragma unroll
  for (int i = 0; i < 16; i += 4) {
    const uint4 v = *(const uint4*)(row + i);
#define UNP(u, k)                                                        \
    {                                                                    \
      const float lo = __uint_as_float((u) << 16);                       \
      const float hi = __uint_as_float((u) & 0xffff0000u);               \
      s = fmaf(lo, as_[ab + (k)], fmaf(hi, as_[ab + (k) + 1], s));       \
      d = fmaf(lo, ad_[ab + (k)], fmaf(hi, ad_[ab + (k) + 1], d));       \
    }
    UNP(v.x, 2 * i) UNP(v.y, 2 * i + 2) UNP(v.z, 2 * i + 4) UNP(v.w, 2 * i + 6)
#undef UNP
  }
  es[idx] = s;
  ed[idx] = d;
}

// ---- CSR build: histogram ----
__global__ __launch_bounds__(256) void hist_k(const int* __restrict__ dst, int* __restrict__ counts) {
  const int i = blockIdx.x * 256 + threadIdx.x;
  if (i < NE) atomicAdd(&counts[dst[i]], 1);
}

// ---- two-level scan ----
__global__ __launch_bounds__(256) void scan_blk_k(const int* __restrict__ counts,
                                                  int* __restrict__ row_start,
                                                  int* __restrict__ blocksum) {
  __shared__ int sm[256];
  const int t = threadIdx.x;
  const int i = blockIdx.x * 256 + t;
  const int c = (i < NN) ? counts[i] : 0;
  sm[t] = c;
  __syncthreads();
#pragma unroll
  for (int off = 1; off < 256; off <<= 1) {
    const int v = (t >= off) ? sm[t - off] : 0;
    __syncthreads();
    sm[t] += v;
    __syncthreads();
  }
  if (i < NN) row_start[i] = sm[t] - c;
  if (t == 255) blocksum[blockIdx.x] = sm[255];
}

__global__ __launch_bounds__(512) void scan_top_k(const int* __restrict__ blocksum,
                                                  int* __restrict__ blockoff) {
  __shared__ int sm[512];
  const int t = threadIdx.x;
  const int c = (t < NBLK) ? blocksum[t] : 0;
  sm[t] = c;
  __syncthreads();
#pragma unroll
  for (int off = 1; off < 512; off <<= 1) {
    const int v = (t >= off) ? sm[t - off] : 0;
    __syncthreads();
    sm[t] += v;
    __syncthreads();
  }
  if (t < NBLK) blockoff[t] = sm[t] - c;
}

__global__ __launch_bounds__(256) void scan_fix_k(int* __restrict__ row_start,
                                                  const int* __restrict__ blockoff,
                                                  int* __restrict__ cursor) {
  const int i = blockIdx.x * 256 + threadIdx.x;
  if (i < NN) {
    const int v = row_start[i] + blockoff[blockIdx.x];
    row_start[i] = v;
    cursor[i] = v;
  }
  if (i == 0) row_start[NN] = NE;
}

__global__ __launch_bounds__(256) void scatter_k(const int* __restrict__ src,
                                                 const int* __restrict__ dst,
                                                 int* __restrict__ cursor,
                                                 int* __restrict__ csr_src) {
  const int i = blockIdx.x * 256 + threadIdx.x;
  if (i >= NE) return;
  const int pos = atomicAdd(&cursor[dst[i]], 1);
  csr_src[pos] = src[i];
}

// ---- fused GAT aggregation: one wave per dst node, bf16 gathers, 8-way ILP ----
#define EDGE_BODY(sv)                                                      \
  {                                                                        \
    const int s_ = (sv);                                                   \
    float v_ = es[s_ * 4 + h] + edh;                                       \
    v_ = v_ > 0.f ? v_ : 0.2f * v_;                                        \
    const float w_ = __expf(v_);                                           \
    const uint m_ = xbf[(size_t)s_ * 64 + l];                              \
    const float mx = __uint_as_float(m_ << 16);                            \
    const float my = __uint_as_float(m_ & 0xffff0000u);                    \
    den += w_;                                                             \
    ax = fmaf(w_, mx, ax);                                                 \
    ay = fmaf(w_, my, ay);                                                 \
  }

__global__ __launch_bounds__(256) void gat_agg_k(const int* __restrict__ row_start,
                                                 const int* __restrict__ csr_src,
                                                 const float* __restrict__ es,
                                                 const float* __restrict__ ed,
                                                 const uint* __restrict__ xbf,
                                                 const float* __restrict__ base,
                                                 const float* __restrict__ bias,
                                                 float* __restrict__ out) {
  const int wid = (blockIdx.x * 256 + threadIdx.x) >> 6;  // node id
  if (wid >= NN) return;
  const int l = threadIdx.x & 63;   // lane: channels 2l (lo), 2l+1 (hi)
  const int h = l >> 4;             // head of both channels
  const float edh = ed[wid * 4 + h];
  const int beg = row_start[wid], end = row_start[wid + 1];
  float ax = 0.f, ay = 0.f, den = 0.f;
  int i = beg;
  for (; i + 8 <= end; i += 8) {
    const int s0 = csr_src[i],     s1 = csr_src[i + 1];
    const int s2 = csr_src[i + 2], s3 = csr_src[i + 3];
    const int s4 = csr_src[i + 4], s5 = csr_src[i + 5];
    const int s6 = csr_src[i + 6], s7 = csr_src[i + 7];
    EDGE_BODY(s0) EDGE_BODY(s1) EDGE_BODY(s2) EDGE_BODY(s3)
    EDGE_BODY(s4) EDGE_BODY(s5) EDGE_BODY(s6) EDGE_BODY(s7)
  }
  for (; i + 4 <= end; i += 4) {
    const int s0 = csr_src[i],     s1 = csr_src[i + 1];
    const int s2 = csr_src[i + 2], s3 = csr_src[i + 3];
    EDGE_BODY(s0) EDGE_BODY(s1) EDGE_BODY(s2) EDGE_BODY(s3)
  }
  for (; i < end; i++) EDGE_BODY(csr_src[i]);

  const float inv = den > 0.f ? 1.f / den : 0.f;
  float rx = ax * inv, ry = ay * inv;
  const int o = wid * 128 + l * 2;
  if (base) { rx += base[o]; ry += base[o + 1]; }
  if (bias) { rx += bias[l * 2]; ry += bias[l * 2 + 1]; }
  *(float2*)(out + o) = make_float2(rx, ry);
}

// ---- final projection: one thread per node, 32 accumulators, w via scalar loads ----
__global__ __launch_bounds__(256) void out_proj_k(const float* __restrict__ h0,
                                                  const float* __restrict__ h1,
                                                  const float* __restrict__ h2,
                                                  const float* __restrict__ opW,
                                                  const float* __restrict__ opb,
                                                  float* __restrict__ out) {
  const int n = blockIdx.x * 256 + threadIdx.x;
  if (n >= NN) return;
  float acc[32];
#pragma unroll
  for (int c = 0; c < 32; c++) acc[c] = opb[c];  // uniform -> scalar loads

  const float4* __restrict__ r0 = (const float4*)(h0 + (size_t)n * 128);
  const float4* __restrict__ r1 = (const float4*)(h1 + (size_t)n * 128);
  const float4* __restrict__ r2 = (const float4*)(h2 + (size_t)n * 128);

#define SEG_STEP(a, kbase)                                                    \
  {                                                                           \
    const float* __restrict__ wr = opW + (kbase) * 32;                        \
    _Pragma("unroll") for (int c = 0; c < 32; c++)                            \
        acc[c] = fmaf((a).x, wr[c], acc[c]);                                  \
    _Pragma("unroll") for (int c = 0; c < 32; c++)                            \
        acc[c] = fmaf((a).y, wr[32 + c], acc[c]);                             \
    _Pragma("unroll") for (int c = 0; c < 32; c++)                            \
        acc[c] = fmaf((a).z, wr[64 + c], acc[c]);                             \
    _Pragma("unroll") for (int c = 0; c < 32; c++)                            \
        acc[c] = fmaf((a).w, wr[96 + c], acc[c]);                             \
  }

  for (int k4 = 0; k4 < 32; k4++) {
    const float4 a = r0[k4];
    SEG_STEP(a, k4 * 4);
  }
  for (int k4 = 0; k4 < 32; k4++) {
    const float4 a = r1[k4];
    SEG_STEP(a, 128 + k4 * 4);
  }
  for (int k4 = 0; k4 < 32; k4++) {
    const float4 a = r2[k4];
    SEG_STEP(a, 256 + k4 * 4);
  }
#undef SEG_STEP

  float* __restrict__ o = out + (size_t)n * 32;
#pragma unroll
  for (int c = 0; c < 32; c += 4)
    *(float4*)(o + c) = make_float4(acc[c], acc[c + 1], acc[c + 2], acc[c + 3]);
}

extern "C" void kernel_launch(void* const* d_in, const int* in_sizes, int n_in,
                              void* d_out, int out_size, void* d_ws, size_t ws_size,
                              hipStream_t stream) {
  (void)in_sizes; (void)n_in; (void)out_size; (void)ws_size;
  const float* x  = (const float*)d_in[0];
  const int*   ei = (const int*)d_in[1];
  const int*  src = ei;
  const int*  dst = ei + NE;
  const float *W0 = (const float*)d_in[2],  *as0 = (const float*)d_in[3],
              *ad0 = (const float*)d_in[4], *b0 = (const float*)d_in[5];
  const float *W1 = (const float*)d_in[6],  *as1 = (const float*)d_in[7],
              *ad1 = (const float*)d_in[8], *b1 = (const float*)d_in[9];
  const float *W2 = (const float*)d_in[10], *as2 = (const float*)d_in[11],
              *ad2 = (const float*)d_in[12], *b2 = (const float*)d_in[13];
  const float *llW = (const float*)d_in[14], *llb = (const float*)d_in[15];
  const float *opW = (const float*)d_in[16], *opb = (const float*)d_in[17];

  float* ws    = (float*)d_ws;
  float* h0f   = ws;             // NHC
  float* h1f   = h0f + NHC;      // NHC
  float* h2f   = h1f + NHC;      // NHC
  uint*  xbf   = (uint*)(h2f + NHC);      // NHC/2 uints (bf16 xh)
  float* es    = (float*)(xbf + NHC / 2); // NH4
  float* ed    = es + NH4;       // NH4
  int* row_start = (int*)(ed + NH4);      // NN+1
  int* cursor    = row_start + NN + 1;    // NN
  int* counts    = cursor + NN;           // NN
  int* csr_src   = counts + NN;           // NE
  int* blocksum  = csr_src + NE;          // NBLK
  int* blockoff  = blocksum + NBLK;       // NBLK

  const dim3 blk(256);
  // ---------- CSR build (edges shared by all 3 layers) ----------
  hipMemsetAsync(counts, 0, (size_t)NN * 4, stream);
  hist_k<<<6250, blk, 0, stream>>>(dst, counts);
  scan_blk_k<<<NBLK, blk, 0, stream>>>(counts, row_start, blocksum);
  scan_top_k<<<1, 512, 0, stream>>>(blocksum, blockoff);
  scan_fix_k<<<NBLK, blk, 0, stream>>>(row_start, blockoff, cursor);
  scatter_k<<<6250, blk, 0, stream>>>(src, dst, cursor, csr_src);
  // ---------- layer 0 ----------
  gemm128_k<true><<<3125, blk, 0, stream>>>(x, W0, xbf, nullptr, nullptr);
  attn_coef_k<<<1563, blk, 0, stream>>>(xbf, as0, ad0, es, ed);
  gat_agg_k<<<25000, blk, 0, stream>>>(row_start, csr_src, es, ed, xbf, nullptr, b0, h0f);
  // ---------- layer 1 ----------
  gemm128_k<true><<<3125, blk, 0, stream>>>(h0f, W1, xbf, nullptr, nullptr);
  attn_coef_k<<<1563, blk, 0, stream>>>(xbf, as1, ad1, es, ed);
  gat_agg_k<<<25000, blk, 0, stream>>>(row_start, csr_src, es, ed, xbf, h0f, b1, h1f);
  // ---------- layer 2 ----------
  gemm128_k<false><<<3125, blk, 0, stream>>>(h1f, llW, h2f, llb, b2);  // h2 base = h1@llW + llb + b2
  gemm128_k<true><<<3125, blk, 0, stream>>>(h1f, W2, xbf, nullptr, nullptr);
  attn_coef_k<<<1563, blk, 0, stream>>>(xbf, as2, ad2, es, ed);
  gat_agg_k<<<25000, blk, 0, stream>>>(row_start, csr_src, es, ed, xbf, h2f, nullptr, h2f);
  // ---------- output head ----------
  out_proj_k<<<391, blk, 0, stream>>>(h0f, h1f, h2f, opW, opb, (float*)d_out);
}

// Round 7
// 776.348 us; speedup vs baseline: 11.6340x; 1.1803x over previous
//
#include <hip/hip_runtime.h>
#include <hip/hip_bf16.h>

#define NN  100000
#define NE  1600000
#define NH4 400000      // N*H
#define NHC 12800000    // N*HC
#define NBLK 391        // ceil(NN/256)
#define SC_CHUNK 2048
#define SC_NCHUNK ((NE + SC_CHUNK - 1) / SC_CHUNK)  // 782

__device__ __forceinline__ ushort f2bf(float f) {  // RNE f32 -> bf16 bits
  uint u = __float_as_uint(f);
  u += 0x7fff + ((u >> 16) & 1);
  return (ushort)(u >> 16);
}

// ---- GEMM: out[N,128] = A[N,128] @ W[128,128] (+ bias1 + bias2) ----
// Tile: 64 rows/block, thread = 16 rows x 2 cols (c2, c2+64). As reads are
// wave-uniform broadcasts; VALU-bound (~256 cyc VALU vs ~238 cyc LDS per k4).
template <bool BF16OUT>
__global__ __launch_bounds__(256) void gemm128_k(const float* __restrict__ A,
                                                 const float* __restrict__ W,
                                                 void* __restrict__ outv,
                                                 const float* __restrict__ bias1,
                                                 const float* __restrict__ bias2) {
  __shared__ float As[64 * 128];   // 32 KB
  __shared__ float Wsh[64 * 128];  // 32 KB
  const int tid = threadIdx.x;
  const int row0 = blockIdx.x * 64;
  {
    const float4* __restrict__ Ag = (const float4*)(A + (size_t)row0 * 128);
    float4* Al = (float4*)As;
#pragma unroll
    for (int i = 0; i < 8; i++) {
      const int idx = tid + 256 * i;          // float4 index; row = idx>>5
      Al[idx] = (row0 + (idx >> 5) < NN) ? Ag[idx] : make_float4(0.f, 0.f, 0.f, 0.f);
    }
  }

  const int c2 = tid & 63;   // cols c2 and c2+64
  const int rh = tid >> 6;   // row group rh*16..+15 (uniform per wave)
  float acc[16][2];
#pragma unroll
  for (int j = 0; j < 16; j++) acc[j][0] = acc[j][1] = 0.f;

  for (int kt = 0; kt < 2; kt++) {
    {
      const float4* __restrict__ Wg = (const float4*)(W + kt * 64 * 128);
      float4* Wl = (float4*)Wsh;
      __syncthreads();
#pragma unroll
      for (int i = 0; i < 8; i++) Wl[tid + 256 * i] = Wg[tid + 256 * i];
      __syncthreads();
    }
#pragma unroll 2
    for (int kk = 0; kk < 64; kk += 4) {
      const int k = kt * 64 + kk;
      float wa[4], wb[4];
#pragma unroll
      for (int q = 0; q < 4; q++) {
        wa[q] = Wsh[(kk + q) * 128 + c2];
        wb[q] = Wsh[(kk + q) * 128 + c2 + 64];
      }
#pragma unroll
      for (int j = 0; j < 16; j++) {
        const float4 a = *(const float4*)&As[(rh * 16 + j) * 128 + k];  // broadcast
        acc[j][0] = fmaf(a.x, wa[0], acc[j][0]);
        acc[j][1] = fmaf(a.x, wb[0], acc[j][1]);
        acc[j][0] = fmaf(a.y, wa[1], acc[j][0]);
        acc[j][1] = fmaf(a.y, wb[1], acc[j][1]);
        acc[j][0] = fmaf(a.z, wa[2], acc[j][0]);
        acc[j][1] = fmaf(a.z, wb[2], acc[j][1]);
        acc[j][0] = fmaf(a.w, wa[3], acc[j][0]);
        acc[j][1] = fmaf(a.w, wb[3], acc[j][1]);
      }
    }
  }
  float ba = 0.f, bb = 0.f;
  if (bias1) { ba += bias1[c2]; bb += bias1[c2 + 64]; }
  if (bias2) { ba += bias2[c2]; bb += bias2[c2 + 64]; }
#pragma unroll
  for (int j = 0; j < 16; j++) {
    const int r = row0 + rh * 16 + j;
    if (r >= NN) break;
    if constexpr (BF16OUT) {
      ushort* out = (ushort*)outv;
      out[(size_t)r * 128 + c2]      = f2bf(acc[j][0] + ba);
      out[(size_t)r * 128 + c2 + 64] = f2bf(acc[j][1] + bb);
    } else {
      float* out = (float*)outv;
      out[(size_t)r * 128 + c2]      = acc[j][0] + ba;
      out[(size_t)r * 128 + c2 + 64] = acc[j][1] + bb;
    }
  }
}

// ---- attention coefficients from bf16 xh ----
__global__ __launch_bounds__(256) void attn_coef_k(const uint* __restrict__ xbf,
                                                   const float* __restrict__ as_,
                                                   const float* __restrict__ ad_,
                                                   float* __restrict__ es,
                                                   float* __restrict__ ed) {
  const int idx = blockIdx.x * 256 + threadIdx.x;
  if (idx >= NH4) return;
  const int h = idx & 3;
  const int ab = h * 32;
  const uint* row = xbf + (size_t)(idx >> 2) * 64 + h * 16;
  float s = 0.f, d = 0.f;
#pragma unroll
  for (int i = 0; i < 16; i += 4) {
    const uint4 v = *(const uint4*)(row + i);
#define UNP(u, k)                                                        \
    {                                                                    \
      const float lo = __uint_as_float((u) << 16);                       \
      const float hi = __uint_as_float((u) & 0xffff0000u);               \
      s = fmaf(lo, as_[ab + (k)], fmaf(hi, as_[ab + (k) + 1], s));       \
      d = fmaf(lo, ad_[ab + (k)], fmaf(hi, ad_[ab + (k) + 1], d));       \
    }
    UNP(v.x, 2 * i) UNP(v.y, 2 * i + 2) UNP(v.z, 2 * i + 4) UNP(v.w, 2 * i + 6)
#undef UNP
  }
  es[idx] = s;
  ed[idx] = d;
}

// ---- CSR build: histogram ----
__global__ __launch_bounds__(256) void hist_k(const int* __restrict__ dst, int* __restrict__ counts) {
  const int i = blockIdx.x * 256 + threadIdx.x;
  if (i < NE) atomicAdd(&counts[dst[i]], 1);
}

// ---- two-level scan ----
__global__ __launch_bounds__(256) void scan_blk_k(const int* __restrict__ counts,
                                                  int* __restrict__ row_start,
                                                  int* __restrict__ blocksum) {
  __shared__ int sm[256];
  const int t = threadIdx.x;
  const int i = blockIdx.x * 256 + t;
  const int c = (i < NN) ? counts[i] : 0;
  sm[t] = c;
  __syncthreads();
#pragma unroll
  for (int off = 1; off < 256; off <<= 1) {
    const int v = (t >= off) ? sm[t - off] : 0;
    __syncthreads();
    sm[t] += v;
    __syncthreads();
  }
  if (i < NN) row_start[i] = sm[t] - c;
  if (t == 255) blocksum[blockIdx.x] = sm[255];
}

__global__ __launch_bounds__(512) void scan_top_k(const int* __restrict__ blocksum,
                                                  int* __restrict__ blockoff) {
  __shared__ int sm[512];
  const int t = threadIdx.x;
  const int c = (t < NBLK) ? blocksum[t] : 0;
  sm[t] = c;
  __syncthreads();
#pragma unroll
  for (int off = 1; off < 512; off <<= 1) {
    const int v = (t >= off) ? sm[t - off] : 0;
    __syncthreads();
    sm[t] += v;
    __syncthreads();
  }
  if (t < NBLK) blockoff[t] = sm[t] - c;
}

__global__ __launch_bounds__(256) void scan_fix_k(int* __restrict__ row_start,
                                                  const int* __restrict__ blockoff,
                                                  int* __restrict__ cursor) {
  const int i = blockIdx.x * 256 + threadIdx.x;
  if (i < NN) {
    const int v = row_start[i] + blockoff[blockIdx.x];
    row_start[i] = v;
    cursor[i] = v;
  }
  if (i == 0) row_start[NN] = NE;
}

// ---- XCD-partitioned scatter: group g = blockIdx&7 handles dst range
// [g*12500,(g+1)*12500); with round-robin block->XCD mapping each XCD's
// csr_src writes stay in its own contiguous ~0.8MB slice (L2-local). ----
__global__ __launch_bounds__(256) void scatter_k(const int* __restrict__ src,
                                                 const int* __restrict__ dst,
                                                 int* __restrict__ cursor,
                                                 int* __restrict__ csr_src) {
  const int g = blockIdx.x & 7;
  const int chunk = blockIdx.x >> 3;
  const int lo = g * (NN / 8);
  const int hi = lo + (NN / 8);
  const int e0 = chunk * SC_CHUNK;
  const int e1 = (e0 + SC_CHUNK < NE) ? e0 + SC_CHUNK : NE;
  for (int i = e0 + threadIdx.x; i < e1; i += 256) {
    const int d = dst[i];
    if (d >= lo && d < hi) {
      const int pos = atomicAdd(&cursor[d], 1);
      csr_src[pos] = src[i];
    }
  }
}

// ---- fused GAT aggregation: one wave per dst node, bf16 gathers, 8-way ILP ----
#define EDGE_BODY(sv)                                                      \
  {                                                                        \
    const int s_ = (sv);                                                   \
    float v_ = es[s_ * 4 + h] + edh;                                       \
    v_ = v_ > 0.f ? v_ : 0.2f * v_;                                        \
    const float w_ = __expf(v_);                                           \
    const uint m_ = xbf[(size_t)s_ * 64 + l];                              \
    const float mx = __uint_as_float(m_ << 16);                            \
    const float my = __uint_as_float(m_ & 0xffff0000u);                    \
    den += w_;                                                             \
    ax = fmaf(w_, mx, ax);                                                 \
    ay = fmaf(w_, my, ay);                                                 \
  }

__global__ __launch_bounds__(256) void gat_agg_k(const int* __restrict__ row_start,
                                                 const int* __restrict__ csr_src,
                                                 const float* __restrict__ es,
                                                 const float* __restrict__ ed,
                                                 const uint* __restrict__ xbf,
                                                 const float* __restrict__ base,
                                                 const float* __restrict__ bias,
                                                 float* __restrict__ out) {
  const int wid = (blockIdx.x * 256 + threadIdx.x) >> 6;  // node id
  if (wid >= NN) return;
  const int l = threadIdx.x & 63;   // lane: channels 2l (lo), 2l+1 (hi)
  const int h = l >> 4;             // head of both channels
  const float edh = ed[wid * 4 + h];
  const int beg = row_start[wid], end = row_start[wid + 1];
  float ax = 0.f, ay = 0.f, den = 0.f;
  int i = beg;
  for (; i + 8 <= end; i += 8) {
    const int s0 = csr_src[i],     s1 = csr_src[i + 1];
    const int s2 = csr_src[i + 2], s3 = csr_src[i + 3];
    const int s4 = csr_src[i + 4], s5 = csr_src[i + 5];
    const int s6 = csr_src[i + 6], s7 = csr_src[i + 7];
    EDGE_BODY(s0) EDGE_BODY(s1) EDGE_BODY(s2) EDGE_BODY(s3)
    EDGE_BODY(s4) EDGE_BODY(s5) EDGE_BODY(s6) EDGE_BODY(s7)
  }
  for (; i + 4 <= end; i += 4) {
    const int s0 = csr_src[i],     s1 = csr_src[i + 1];
    const int s2 = csr_src[i + 2], s3 = csr_src[i + 3];
    EDGE_BODY(s0) EDGE_BODY(s1) EDGE_BODY(s2) EDGE_BODY(s3)
  }
  for (; i < end; i++) EDGE_BODY(csr_src[i]);

  const float inv = den > 0.f ? 1.f / den : 0.f;
  float rx = ax * inv, ry = ay * inv;
  const int o = wid * 128 + l * 2;
  if (base) { rx += base[o]; ry += base[o + 1]; }
  if (bias) { rx += bias[l * 2]; ry += bias[l * 2 + 1]; }
  *(float2*)(out + o) = make_float2(rx, ry);
}

// ---- final projection: one thread per node, 32 accumulators, w via scalar loads ----
__global__ __launch_bounds__(256) void out_proj_k(const float* __restrict__ h0,
                                                  const float* __restrict__ h1,
                                                  const float* __restrict__ h2,
                                                  const float* __restrict__ opW,
                                                  const float* __restrict__ opb,
                                                  float* __restrict__ out) {
  const int n = blockIdx.x * 256 + threadIdx.x;
  if (n >= NN) return;
  float acc[32];
#pragma unroll
  for (int c = 0; c < 32; c++) acc[c] = opb[c];  // uniform -> scalar loads

  const float4* __restrict__ r0 = (const float4*)(h0 + (size_t)n * 128);
  const float4* __restrict__ r1 = (const float4*)(h1 + (size_t)n * 128);
  const float4* __restrict__ r2 = (const float4*)(h2 + (size_t)n * 128);

#define SEG_STEP(a, kbase)                                                    \
  {                                                                           \
    const float* __restrict__ wr = opW + (kbase) * 32;                        \
    _Pragma("unroll") for (int c = 0; c < 32; c++)                            \
        acc[c] = fmaf((a).x, wr[c], acc[c]);                                  \
    _Pragma("unroll") for (int c = 0; c < 32; c++)                            \
        acc[c] = fmaf((a).y, wr[32 + c], acc[c]);                             \
    _Pragma("unroll") for (int c = 0; c < 32; c++)                            \
        acc[c] = fmaf((a).z, wr[64 + c], acc[c]);                             \
    _Pragma("unroll") for (int c = 0; c < 32; c++)                            \
        acc[c] = fmaf((a).w, wr[96 + c], acc[c]);                             \
  }

  for (int k4 = 0; k4 < 32; k4++) {
    const float4 a = r0[k4];
    SEG_STEP(a, k4 * 4);
  }
  for (int k4 = 0; k4 < 32; k4++) {
    const float4 a = r1[k4];
    SEG_STEP(a, 128 + k4 * 4);
  }
  for (int k4 = 0; k4 < 32; k4++) {
    const float4 a = r2[k4];
    SEG_STEP(a, 256 + k4 * 4);
  }
#undef SEG_STEP

  float* __restrict__ o = out + (size_t)n * 32;
#pragma unroll
  for (int c = 0; c < 32; c += 4)
    *(float4*)(o + c) = make_float4(acc[c], acc[c + 1], acc[c + 2], acc[c + 3]);
}

extern "C" void kernel_launch(void* const* d_in, const int* in_sizes, int n_in,
                              void* d_out, int out_size, void* d_ws, size_t ws_size,
                              hipStream_t stream) {
  (void)in_sizes; (void)n_in; (void)out_size; (void)ws_size;
  const float* x  = (const float*)d_in[0];
  const int*   ei = (const int*)d_in[1];
  const int*  src = ei;
  const int*  dst = ei + NE;
  const float *W0 = (const float*)d_in[2],  *as0 = (const float*)d_in[3],
              *ad0 = (const float*)d_in[4], *b0 = (const float*)d_in[5];
  const float *W1 = (const float*)d_in[6],  *as1 = (const float*)d_in[7],
              *ad1 = (const float*)d_in[8], *b1 = (const float*)d_in[9];
  const float *W2 = (const float*)d_in[10], *as2 = (const float*)d_in[11],
              *ad2 = (const float*)d_in[12], *b2 = (const float*)d_in[13];
  const float *llW = (const float*)d_in[14], *llb = (const float*)d_in[15];
  const float *opW = (const float*)d_in[16], *opb = (const float*)d_in[17];

  float* ws    = (float*)d_ws;
  float* h0f   = ws;             // NHC
  float* h1f   = h0f + NHC;      // NHC
  float* h2f   = h1f + NHC;      // NHC
  uint*  xbf   = (uint*)(h2f + NHC);      // NHC/2 uints (bf16 xh)
  float* es    = (float*)(xbf + NHC / 2); // NH4
  float* ed    = es + NH4;       // NH4
  int* row_start = (int*)(ed + NH4);      // NN+1
  int* cursor    = row_start + NN + 1;    // NN
  int* counts    = cursor + NN;           // NN
  int* csr_src   = counts + NN;           // NE
  int* blocksum  = csr_src + NE;          // NBLK
  int* blockoff  = blocksum + NBLK;       // NBLK

  const dim3 blk(256);
  // ---------- CSR build (edges shared by all 3 layers) ----------
  hipMemsetAsync(counts, 0, (size_t)NN * 4, stream);
  hist_k<<<6250, blk, 0, stream>>>(dst, counts);
  scan_blk_k<<<NBLK, blk, 0, stream>>>(counts, row_start, blocksum);
  scan_top_k<<<1, 512, 0, stream>>>(blocksum, blockoff);
  scan_fix_k<<<NBLK, blk, 0, stream>>>(row_start, blockoff, cursor);
  scatter_k<<<SC_NCHUNK * 8, blk, 0, stream>>>(src, dst, cursor, csr_src);
  // ---------- layer 0 ----------
  gemm128_k<true><<<1563, blk, 0, stream>>>(x, W0, xbf, nullptr, nullptr);
  attn_coef_k<<<1563, blk, 0, stream>>>(xbf, as0, ad0, es, ed);
  gat_agg_k<<<25000, blk, 0, stream>>>(row_start, csr_src, es, ed, xbf, nullptr, b0, h0f);
  // ---------- layer 1 ----------
  gemm128_k<true><<<1563, blk, 0, stream>>>(h0f, W1, xbf, nullptr, nullptr);
  attn_coef_k<<<1563, blk, 0, stream>>>(xbf, as1, ad1, es, ed);
  gat_agg_k<<<25000, blk, 0, stream>>>(row_start, csr_src, es, ed, xbf, h0f, b1, h1f);
  // ---------- layer 2 ----------
  gemm128_k<false><<<1563, blk, 0, stream>>>(h1f, llW, h2f, llb, b2);  // h2 base = h1@llW + llb + b2
  gemm128_k<true><<<1563, blk, 0, stream>>>(h1f, W2, xbf, nullptr, nullptr);
  attn_coef_k<<<1563, blk, 0, stream>>>(xbf, as2, ad2, es, ed);
  gat_agg_k<<<25000, blk, 0, stream>>>(row_start, csr_src, es, ed, xbf, h2f, nullptr, h2f);
  // ---------- output head ----------
  out_proj_k<<<391, blk, 0, stream>>>(h0f, h1f, h2f, opW, opb, (float*)d_out);
}